// Round 1
// baseline (113.929 us; speedup 1.0000x reference)
//
#include <hip/hip_runtime.h>
#include <hip/hip_bf16.h>

// HybridSurvivalQ: quantum expval collapses to prod_{q=1..6} cos(x_q[q]+p[q])
// (CNOT ring only permutes basis states; final bit0 = parity of bits 1..6,
//  and E[(-1)^{b_q}] = cos^2 - sin^2 = cos(x+p) per qubit; qubit 0 marginalizes to 1).
// Then a tiny MLP 65->32->16->1 with ReLU. One thread per row, fp32 vector ALU
// (no fp32 MFMA on CDNA4; memory floor ~6.3us dominates anyway).

#define NQ 7
#define F  64
#define H1 32
#define H2 16

__global__ __launch_bounds__(256) void hybrid_fused(
    const float* __restrict__ x_q, const float* __restrict__ x_c,
    const float* __restrict__ q_params,
    const float* __restrict__ W1, const float* __restrict__ b1,
    const float* __restrict__ W2, const float* __restrict__ b2,
    const float* __restrict__ W3, const float* __restrict__ b3,
    float* __restrict__ out, int B)
{
    const int row = blockIdx.x * 256 + threadIdx.x;
    if (row >= B) return;

    // ---- quantum expectation (closed form) ----
    float qv = 1.0f;
    #pragma unroll
    for (int q = 1; q < NQ; ++q) {
        qv *= __cosf(x_q[(size_t)row * NQ + q] + q_params[q]);
    }

    // ---- layer 1: combined(65) @ W1(65x32) + b1, ReLU ----
    // combined[0] = qv, combined[1+f] = x_c[f]
    float acc1[H1];
    #pragma unroll
    for (int j = 0; j < H1; ++j)
        acc1[j] = fmaf(qv, W1[j], b1[j]);   // k = 0 row of W1

    const float4* xc4 = reinterpret_cast<const float4*>(x_c + (size_t)row * F);
    #pragma unroll
    for (int k4 = 0; k4 < F / 4; ++k4) {
        const float4 xv = xc4[k4];
        const float* w = W1 + (size_t)(1 + 4 * k4) * H1;  // uniform addr -> s_load
        #pragma unroll
        for (int j = 0; j < H1; ++j) acc1[j] = fmaf(xv.x, w[j],          acc1[j]);
        #pragma unroll
        for (int j = 0; j < H1; ++j) acc1[j] = fmaf(xv.y, w[H1 + j],     acc1[j]);
        #pragma unroll
        for (int j = 0; j < H1; ++j) acc1[j] = fmaf(xv.z, w[2 * H1 + j], acc1[j]);
        #pragma unroll
        for (int j = 0; j < H1; ++j) acc1[j] = fmaf(xv.w, w[3 * H1 + j], acc1[j]);
    }

    // ---- layer 2: relu(acc1)(32) @ W2(32x16) + b2, ReLU ----
    float acc2[H2];
    #pragma unroll
    for (int j = 0; j < H2; ++j) acc2[j] = b2[j];
    #pragma unroll
    for (int k = 0; k < H1; ++k) {
        const float h = fmaxf(acc1[k], 0.0f);
        #pragma unroll
        for (int j = 0; j < H2; ++j)
            acc2[j] = fmaf(h, W2[(size_t)k * H2 + j], acc2[j]);
    }

    // ---- layer 3: relu(acc2)(16) @ W3(16x1) + b3 ----
    float o = b3[0];
    #pragma unroll
    for (int k = 0; k < H2; ++k)
        o = fmaf(fmaxf(acc2[k], 0.0f), W3[k], o);

    out[row] = o;
}

extern "C" void kernel_launch(void* const* d_in, const int* in_sizes, int n_in,
                              void* d_out, int out_size, void* d_ws, size_t ws_size,
                              hipStream_t stream) {
    const float* x_q      = (const float*)d_in[0];
    const float* x_c      = (const float*)d_in[1];
    const float* q_params = (const float*)d_in[2];
    const float* W1       = (const float*)d_in[3];
    const float* b1       = (const float*)d_in[4];
    const float* W2       = (const float*)d_in[5];
    const float* b2       = (const float*)d_in[6];
    const float* W3       = (const float*)d_in[7];
    const float* b3       = (const float*)d_in[8];
    float* out = (float*)d_out;

    const int B = in_sizes[0] / NQ;   // 131072
    const int grid = (B + 255) / 256; // 512 blocks of 256

    hybrid_fused<<<grid, 256, 0, stream>>>(x_q, x_c, q_params,
                                           W1, b1, W2, b2, W3, b3,
                                           out, B);
}

// Round 3
// 102.221 us; speedup vs baseline: 1.1145x; 1.1145x over previous
//
#include <hip/hip_runtime.h>
#include <hip/hip_bf16.h>

// HybridSurvivalQ: quantum expval collapses to prod_{q=1..6} cos(x_q[q]+p[q])
// (CNOT ring permutes basis states; final bit0 = parity of bits 1..6;
//  E[(-1)^{b_q}] = cos^2-sin^2 = cos(x+p) per qubit; qubit 0 marginalizes out).
// Then MLP 65->32->16->1 with ReLU. One thread per row, fp32 vector ALU.
//
// R1 lesson: dur_us (~113us) is dominated by harness reset fills (268MB d_ws
//   poisons, 42-45us each); our kernel is <42us and invisible in top-5.
// R2 lesson: rolled layer-2 loop indexed acc1[k] with runtime k -> array
//   spilled to scratch; scratch + graph-replay produced post-timing-only
//   divergence. NO runtime-indexed per-thread arrays allowed.
// Structure: layer-1 k-loop rolled (s_load_dwordx16 weight batches, 128-FMA
//   body), layer-2/3 fully unrolled (constant indices -> pure registers).

#define NQ 7
#define F  64
#define H1 32
#define H2 16

__global__ __launch_bounds__(256) void hybrid_fused(
    const float* __restrict__ x_q, const float* __restrict__ x_c,
    const float* __restrict__ q_params,
    const float* __restrict__ W1, const float* __restrict__ b1,
    const float* __restrict__ W2, const float* __restrict__ b2,
    const float* __restrict__ W3, const float* __restrict__ b3,
    float* __restrict__ out, int B)
{
    const int row = blockIdx.x * 256 + threadIdx.x;
    if (row >= B) return;

    // ---- quantum expectation (closed form) ----
    float qv = 1.0f;
    #pragma unroll
    for (int q = 1; q < NQ; ++q) {
        qv *= __cosf(x_q[(size_t)row * NQ + q] + q_params[q]);
    }

    // ---- layer 1: combined(65) @ W1(65x32) + b1 ----
    // combined[0] = qv, combined[1+f] = x_c[f]
    float acc1[H1];
    #pragma unroll
    for (int j = 0; j < H1; ++j)
        acc1[j] = fmaf(qv, W1[j], b1[j]);   // k = 0 row of W1 (constant idx)

    const float4* xc4 = reinterpret_cast<const float4*>(x_c + (size_t)row * F);
    #pragma unroll 1   // rolled: 16 iters; body = 4 s_load batches + 128 FMA
    for (int k4 = 0; k4 < F / 4; ++k4) {
        const float4 xv = xc4[k4];
        const float* w = W1 + (size_t)(1 + 4 * k4) * H1;  // wave-uniform -> s_load
        #pragma unroll
        for (int j = 0; j < H1; ++j) acc1[j] = fmaf(xv.x, w[j],          acc1[j]);
        #pragma unroll
        for (int j = 0; j < H1; ++j) acc1[j] = fmaf(xv.y, w[H1 + j],     acc1[j]);
        #pragma unroll
        for (int j = 0; j < H1; ++j) acc1[j] = fmaf(xv.z, w[2 * H1 + j], acc1[j]);
        #pragma unroll
        for (int j = 0; j < H1; ++j) acc1[j] = fmaf(xv.w, w[3 * H1 + j], acc1[j]);
    }

    // ---- layer 2: relu(acc1)(32) @ W2(32x16) + b2 ----
    // FULLY unrolled: all acc1/acc2 indices constant -> registers, no scratch.
    float acc2[H2];
    #pragma unroll
    for (int j = 0; j < H2; ++j) acc2[j] = b2[j];
    #pragma unroll
    for (int k = 0; k < H1; ++k) {
        const float h = fmaxf(acc1[k], 0.0f);
        #pragma unroll
        for (int j = 0; j < H2; ++j)
            acc2[j] = fmaf(h, W2[k * H2 + j], acc2[j]);
    }

    // ---- layer 3: relu(acc2)(16) @ W3(16x1) + b3 ----
    float o = b3[0];
    #pragma unroll
    for (int k = 0; k < H2; ++k)
        o = fmaf(fmaxf(acc2[k], 0.0f), W3[k], o);

    out[row] = o;
}

extern "C" void kernel_launch(void* const* d_in, const int* in_sizes, int n_in,
                              void* d_out, int out_size, void* d_ws, size_t ws_size,
                              hipStream_t stream) {
    const float* x_q      = (const float*)d_in[0];
    const float* x_c      = (const float*)d_in[1];
    const float* q_params = (const float*)d_in[2];
    const float* W1       = (const float*)d_in[3];
    const float* b1       = (const float*)d_in[4];
    const float* W2       = (const float*)d_in[5];
    const float* b2       = (const float*)d_in[6];
    const float* W3       = (const float*)d_in[7];
    const float* b3       = (const float*)d_in[8];
    float* out = (float*)d_out;

    const int B = in_sizes[0] / NQ;   // 131072
    const int grid = (B + 255) / 256; // 512 blocks of 256

    hybrid_fused<<<grid, 256, 0, stream>>>(x_q, x_c, q_params,
                                           W1, b1, W2, b2, W3, b3,
                                           out, B);
}